// Round 1
// baseline (742.214 us; speedup 1.0000x reference)
//
#include <hip/hip_runtime.h>
#include <cstdint>
#include <cstddef>

// InvariantPointAttention, N=768, H=12, C=384, PD=128, SQK=SV=16, PQK=4, PV=8
// All fp32. Multi-kernel decomposition; logits/attn (28 MB) staged in d_ws.

#define N_RES 768
#define NHEAD 12
#define NN (768*768)

__device__ __forceinline__ float softplusf(float x) {
  return (x > 20.f) ? x : log1pf(__expf(x));
}

// ---------------- generic tiled GEMM: C[M,N] = A[M,K] @ B[K,N] + bias[N] ----
// BM=BN=64, BK=16, 256 threads, 4x4 micro-tile. M%64==0, K%16==0 assumed.
__global__ __launch_bounds__(256) void gemm_bias_kernel(
    const float* __restrict__ A, int lda,
    const float* __restrict__ B, int ldb,
    const float* __restrict__ bias,
    float* __restrict__ C, int ldc,
    int M, int Ncols, int K)
{
  __shared__ float As[16][65];
  __shared__ float Bs[16][65];
  const int tid = threadIdx.x;
  const int m0 = blockIdx.y * 64, n0 = blockIdx.x * 64;
  const int tn = tid & 15, tm = tid >> 4;
  float acc[4][4] = {};
  for (int k0 = 0; k0 < K; k0 += 16) {
    { // A tile 64x16
      int idx = tid * 4;
      int m = idx >> 4, k = idx & 15;
      float4 a = *(const float4*)(A + (size_t)(m0 + m) * lda + k0 + k);
      As[k+0][m] = a.x; As[k+1][m] = a.y; As[k+2][m] = a.z; As[k+3][m] = a.w;
    }
    { // B tile 16x64 (guard N edge)
      int idx = tid * 4;
      int k = idx >> 6, n = idx & 63;
      const float* bp = B + (size_t)(k0 + k) * ldb + n0 + n;
      float4 b;
      if (n0 + n + 3 < Ncols) {
        b = *(const float4*)bp;
      } else {
        b.x = (n0+n+0 < Ncols) ? bp[0] : 0.f;
        b.y = (n0+n+1 < Ncols) ? bp[1] : 0.f;
        b.z = (n0+n+2 < Ncols) ? bp[2] : 0.f;
        b.w = (n0+n+3 < Ncols) ? bp[3] : 0.f;
      }
      Bs[k][n+0] = b.x; Bs[k][n+1] = b.y; Bs[k][n+2] = b.z; Bs[k][n+3] = b.w;
    }
    __syncthreads();
    #pragma unroll
    for (int k = 0; k < 16; ++k) {
      float a[4], b[4];
      #pragma unroll
      for (int r = 0; r < 4; ++r) a[r] = As[k][tm*4 + r];
      #pragma unroll
      for (int c = 0; c < 4; ++c) b[c] = Bs[k][tn*4 + c];
      #pragma unroll
      for (int r = 0; r < 4; ++r)
        #pragma unroll
        for (int c = 0; c < 4; ++c)
          acc[r][c] = fmaf(a[r], b[c], acc[r][c]);
    }
    __syncthreads();
  }
  #pragma unroll
  for (int r = 0; r < 4; ++r) {
    int m = m0 + tm*4 + r;
    #pragma unroll
    for (int c = 0; c < 4; ++c) {
      int n = n0 + tn*4 + c;
      if (n < Ncols) C[(size_t)m * ldc + n] = acc[r][c] + bias[n];
    }
  }
}

// ---------------- point projections -> rigid-transformed q_pt/k_pt/v_pt ----
// qpt[h][i][12] (d*4+p), kpt[h][j][12], vpt[h][j][24] (d*8+p), plus sq-norms.
__global__ __launch_bounds__(256) void point_transform_kernel(
    const float* __restrict__ proj_qp, const float* __restrict__ proj_kvp,
    const float* __restrict__ rot, const float* __restrict__ tra,
    float* __restrict__ qpt, float* __restrict__ kpt, float* __restrict__ vpt,
    float* __restrict__ qn, float* __restrict__ kn)
{
  int idx = blockIdx.x * 256 + threadIdx.x;
  if (idx >= N_RES * NHEAD) return;
  int i = idx / NHEAD, h = idx % NHEAD;
  float R[9], T[3];
  #pragma unroll
  for (int r = 0; r < 9; ++r) R[r] = rot[r * N_RES + i];
  #pragma unroll
  for (int d = 0; d < 3; ++d) T[d] = tra[d * N_RES + i];
  float qsum = 0.f;
  #pragma unroll
  for (int p = 0; p < 4; ++p) {
    float x = proj_qp[(size_t)i*144 +      h*4 + p];
    float y = proj_qp[(size_t)i*144 + 48 + h*4 + p];
    float z = proj_qp[(size_t)i*144 + 96 + h*4 + p];
    #pragma unroll
    for (int d = 0; d < 3; ++d) {
      float v = R[3*d]*x + R[3*d+1]*y + R[3*d+2]*z + T[d];
      qpt[((size_t)h*N_RES + i)*12 + d*4 + p] = v;
      qsum += v*v;
    }
  }
  qn[h*N_RES + i] = qsum;
  float ksum = 0.f;
  #pragma unroll
  for (int m = 0; m < 12; ++m) {
    float x = proj_kvp[(size_t)i*432 +       h*12 + m];
    float y = proj_kvp[(size_t)i*432 + 144 + h*12 + m];
    float z = proj_kvp[(size_t)i*432 + 288 + h*12 + m];
    #pragma unroll
    for (int d = 0; d < 3; ++d) {
      float v = R[3*d]*x + R[3*d+1]*y + R[3*d+2]*z + T[d];
      if (m < 4) { kpt[((size_t)h*N_RES + i)*12 + d*4 + m] = v; ksum += v*v; }
      else       { vpt[((size_t)h*N_RES + i)*24 + d*8 + (m-4)] = v; }
    }
  }
  kn[h*N_RES + i] = ksum;
}

// ---------------- scalar+point logits as rank-28 GEMM per head -------------
// logit = sw*qs.ks + pw*qpt.kpt - 0.5*pw*(|qpt|^2+|kpt|^2) + s3*b2d - 50(1-mimj)
__global__ __launch_bounds__(256) void logits_sp_kernel(
    const float* __restrict__ proj_q, const float* __restrict__ proj_kv,
    const float* __restrict__ qpt, const float* __restrict__ kpt,
    const float* __restrict__ qn, const float* __restrict__ kn,
    const float* __restrict__ tpw, const float* __restrict__ b2d,
    const float* __restrict__ mask, float* __restrict__ logits)
{
  const int h = blockIdx.z;
  const int i0 = blockIdx.y * 64, j0 = blockIdx.x * 64;
  __shared__ float U[64][29];
  __shared__ float V[64][29];
  const int tid = threadIdx.x;
  const float pw = 0.13608276348795434f * softplusf(tpw[h]); // sqrt(1/54)*softplus
  const float sw = 0.14433756729740643f; // sqrt(1/48)
  const float s3 = 0.5773502691896258f;  // sqrt(1/3)
  for (int idx = tid; idx < 64*16; idx += 256) {
    int ii = idx >> 4, c = idx & 15;
    U[ii][c] = sw * proj_q[(size_t)(i0+ii)*192 + h*16 + c];
    V[ii][c] = proj_kv[(size_t)(j0+ii)*384 + h*32 + c];
  }
  for (int idx = tid; idx < 64*12; idx += 256) {
    int ii = idx / 12, m = idx % 12;
    U[ii][16+m] = pw * qpt[((size_t)h*N_RES + i0+ii)*12 + m];
    V[ii][16+m] = kpt[((size_t)h*N_RES + j0+ii)*12 + m];
  }
  __syncthreads();
  const int tn = tid & 15, tm = tid >> 4;
  float acc[4][4] = {};
  #pragma unroll
  for (int k = 0; k < 28; ++k) {
    float a[4], b[4];
    #pragma unroll
    for (int r = 0; r < 4; ++r) a[r] = U[tm*4 + r][k];
    #pragma unroll
    for (int c = 0; c < 4; ++c) b[c] = V[tn*4 + c][k];
    #pragma unroll
    for (int r = 0; r < 4; ++r)
      #pragma unroll
      for (int c = 0; c < 4; ++c)
        acc[r][c] = fmaf(a[r], b[c], acc[r][c]);
  }
  const float base = s3 * b2d[h];
  #pragma unroll
  for (int r = 0; r < 4; ++r) {
    int i = i0 + tm*4 + r;
    float qni = qn[h*N_RES + i];
    float mi = mask[i];
    #pragma unroll
    for (int c = 0; c < 4; ++c) {
      int j = j0 + tn*4 + c;
      float l = acc[r][c] - 0.5f*pw*(qni + kn[h*N_RES + j]) + base
                - 50.f*(1.f - mi*mask[j]);
      logits[(size_t)h*NN + (size_t)i*N_RES + j] = l;
    }
  }
}

// ---------------- att2d accumulate: logits += s3 * (in2d @ w2d) -------------
// 4 lanes per (i,j) pair, 32 channels each, shfl reduce. One i per block, 64 j.
__global__ __launch_bounds__(256) void att2d_kernel(
    const float* __restrict__ in2d, const float* __restrict__ w2d,
    float* __restrict__ logits)
{
  __shared__ float w2s[128*12];
  const int tid = threadIdx.x;
  for (int idx = tid; idx < 1536; idx += 256) w2s[idx] = w2d[idx];
  __syncthreads();
  const int i = blockIdx.y;
  const int j = blockIdx.x * 64 + (tid >> 2);
  const int t = tid & 3;
  const float* row = in2d + ((size_t)i * N_RES + j) * 128;
  float acc[12] = {};
  #pragma unroll
  for (int k = 0; k < 8; ++k) {
    int c = k*16 + t*4;
    float4 x = *(const float4*)(row + c);
    const float* w = &w2s[c*12];
    #pragma unroll
    for (int hh = 0; hh < 12; ++hh) acc[hh] = fmaf(x.x, w[hh],    acc[hh]);
    #pragma unroll
    for (int hh = 0; hh < 12; ++hh) acc[hh] = fmaf(x.y, w[12+hh], acc[hh]);
    #pragma unroll
    for (int hh = 0; hh < 12; ++hh) acc[hh] = fmaf(x.z, w[24+hh], acc[hh]);
    #pragma unroll
    for (int hh = 0; hh < 12; ++hh) acc[hh] = fmaf(x.w, w[36+hh], acc[hh]);
  }
  #pragma unroll
  for (int hh = 0; hh < 12; ++hh) {
    float s = acc[hh];
    s += __shfl_xor(s, 1);
    s += __shfl_xor(s, 2);
    acc[hh] = s;
  }
  if (t == 0) {
    const float s3 = 0.5773502691896258f;
    float* lp = logits + (size_t)i * N_RES + j;
    #pragma unroll
    for (int hh = 0; hh < 12; ++hh) lp[(size_t)hh * NN] += s3 * acc[hh];
  }
}

// ---------------- fused softmax (per (h,i) row) + res2d ---------------------
// Block per i. attn rows in LDS; normalized attn written back for later AV.
__global__ __launch_bounds__(256) void softmax_res2d_kernel(
    const float* __restrict__ in2d, float* __restrict__ attn,
    float* __restrict__ feat)
{
  __shared__ float att[12][768];
  __shared__ float comb[12][128];
  const int i = blockIdx.x;
  const int tid = threadIdx.x;
  for (int idx = tid; idx < 12*768; idx += 256) {
    int h = idx / 768, j = idx % 768;
    att[h][j] = attn[(size_t)h*NN + (size_t)i*N_RES + j];
  }
  __syncthreads();
  const int wid = tid >> 6, lane = tid & 63;
  for (int r = 0; r < 3; ++r) {
    const int h = wid*3 + r;
    float m = -1e30f;
    for (int j = lane; j < 768; j += 64) m = fmaxf(m, att[h][j]);
    #pragma unroll
    for (int off = 32; off; off >>= 1) m = fmaxf(m, __shfl_xor(m, off));
    float s = 0.f;
    for (int j = lane; j < 768; j += 64) {
      float e = __expf(att[h][j] - m);
      att[h][j] = e;
      s += e;
    }
    #pragma unroll
    for (int off = 32; off; off >>= 1) s += __shfl_xor(s, off);
    float inv = 1.0f / s;
    for (int j = lane; j < 768; j += 64) att[h][j] *= inv;
  }
  __syncthreads();
  for (int idx = tid; idx < 12*768; idx += 256) {
    int h = idx / 768, j = idx % 768;
    attn[(size_t)h*NN + (size_t)i*N_RES + j] = att[h][j];
  }
  // res2d: channel per thread (mod 128), 2-way j split
  const int c = tid & 127, jj = tid >> 7;
  const float* base = in2d + (size_t)i * N_RES * 128 + c;
  float acc[12] = {};
  for (int j = jj; j < 768; j += 2) {
    float x = base[(size_t)j * 128];
    #pragma unroll
    for (int h = 0; h < 12; ++h) acc[h] = fmaf(att[h][j], x, acc[h]);
  }
  if (jj == 1) {
    #pragma unroll
    for (int h = 0; h < 12; ++h) comb[h][c] = acc[h];
  }
  __syncthreads();
  if (jj == 0) {
    float* f = feat + (size_t)i*2112 + 576;
    #pragma unroll
    for (int h = 0; h < 12; ++h) f[h*128 + c] = acc[h] + comb[h][c];
  }
}

// ---------------- attn @ [vs | v_pt] per head (40 cols) ---------------------
__global__ __launch_bounds__(256) void res_sv_pt_kernel(
    const float* __restrict__ attn, const float* __restrict__ proj_kv,
    const float* __restrict__ vpt, float* __restrict__ feat,
    float* __restrict__ rpt)
{
  __shared__ float at[32][132];
  __shared__ float vt[128][41];
  const int h = blockIdx.x;
  const int i0 = blockIdx.y * 32;
  const int tid = threadIdx.x;
  const int tn = tid & 15, tm = tid >> 4;
  float acc[2][3] = {};
  for (int j0 = 0; j0 < 768; j0 += 128) {
    for (int t = tid; t < 32*32; t += 256) {
      int ii = t >> 5, jf = t & 31;
      float4 v = *(const float4*)(attn + (size_t)h*NN + (size_t)(i0+ii)*N_RES + j0 + jf*4);
      at[ii][jf*4+0] = v.x; at[ii][jf*4+1] = v.y;
      at[ii][jf*4+2] = v.z; at[ii][jf*4+3] = v.w;
    }
    for (int t = tid; t < 128*16; t += 256) {
      int jj = t >> 4, c = t & 15;
      vt[jj][c] = proj_kv[(size_t)(j0+jj)*384 + h*32 + 16 + c];
    }
    for (int t = tid; t < 128*24; t += 256) {
      int jj = t / 24, m = t % 24;
      vt[jj][16+m] = vpt[((size_t)h*N_RES + j0+jj)*24 + m];
    }
    __syncthreads();
    #pragma unroll 4
    for (int jj = 0; jj < 128; ++jj) {
      float a0 = at[tm*2+0][jj], a1 = at[tm*2+1][jj];
      float b0 = vt[jj][tn*3+0], b1 = vt[jj][tn*3+1], b2 = vt[jj][tn*3+2];
      acc[0][0] = fmaf(a0, b0, acc[0][0]);
      acc[0][1] = fmaf(a0, b1, acc[0][1]);
      acc[0][2] = fmaf(a0, b2, acc[0][2]);
      acc[1][0] = fmaf(a1, b0, acc[1][0]);
      acc[1][1] = fmaf(a1, b1, acc[1][1]);
      acc[1][2] = fmaf(a1, b2, acc[1][2]);
    }
    __syncthreads();
  }
  #pragma unroll
  for (int r = 0; r < 2; ++r) {
    int i = i0 + tm*2 + r;
    #pragma unroll
    for (int c = 0; c < 3; ++c) {
      int col = tn*3 + c;
      if (col < 16)       feat[(size_t)i*2112 + h*16 + col] = acc[r][c];
      else if (col < 40)  rpt[((size_t)i*NHEAD + h)*24 + (col-16)] = acc[r][c];
    }
  }
}

// ---------------- point epilogue: inverse rigid + dist ----------------------
__global__ __launch_bounds__(256) void pt_epilogue_kernel(
    const float* __restrict__ rpt,
    const float* __restrict__ rot, const float* __restrict__ tra,
    float* __restrict__ feat)
{
  int idx = blockIdx.x * 256 + threadIdx.x;
  if (idx >= N_RES * 96) return;
  int i = idx / 96, m = idx % 96;
  int h = m >> 3, p = m & 7;
  const float* rp = rpt + ((size_t)i*NHEAD + h)*24 + p;
  float gx = rp[0]  - tra[i];
  float gy = rp[8]  - tra[N_RES + i];
  float gz = rp[16] - tra[2*N_RES + i];
  float lx = rot[0*N_RES+i]*gx + rot[3*N_RES+i]*gy + rot[6*N_RES+i]*gz;
  float ly = rot[1*N_RES+i]*gx + rot[4*N_RES+i]*gy + rot[7*N_RES+i]*gz;
  float lz = rot[2*N_RES+i]*gx + rot[5*N_RES+i]*gy + rot[8*N_RES+i]*gz;
  float dist = sqrtf(1e-8f + lx*lx + ly*ly + lz*lz);
  float* f = feat + (size_t)i*2112 + 192;
  f[m]       = lx;
  f[96 + m]  = ly;
  f[192 + m] = lz;
  f[288 + m] = dist;
}

extern "C" void kernel_launch(void* const* d_in, const int* in_sizes, int n_in,
                              void* d_out, int out_size, void* d_ws, size_t ws_size,
                              hipStream_t stream)
{
  const float* in1d = (const float*)d_in[0];
  const float* in2d = (const float*)d_in[1];
  const float* mask = (const float*)d_in[2];
  const float* rot  = (const float*)d_in[3];
  const float* tra  = (const float*)d_in[4];
  const float* wq   = (const float*)d_in[5];
  const float* bq   = (const float*)d_in[6];
  const float* wkv  = (const float*)d_in[7];
  const float* bkv  = (const float*)d_in[8];
  const float* wqp  = (const float*)d_in[9];
  const float* bqp  = (const float*)d_in[10];
  const float* wkvp = (const float*)d_in[11];
  const float* bkvp = (const float*)d_in[12];
  const float* tpw  = (const float*)d_in[13];
  const float* w2d  = (const float*)d_in[14];
  const float* b2d  = (const float*)d_in[15];
  const float* wout = (const float*)d_in[16];
  const float* bout = (const float*)d_in[17];
  float* out = (float*)d_out;

  float* ws = (float*)d_ws;
  float* proj_q   = ws;                  // 768*192   = 147456
  float* proj_kv  = proj_q   + 147456;   // 768*384   = 294912
  float* proj_qp  = proj_kv  + 294912;   // 768*144   = 110592
  float* proj_kvp = proj_qp  + 110592;   // 768*432   = 331776
  float* qpt      = proj_kvp + 331776;   // 12*768*12 = 110592
  float* kpt      = qpt      + 110592;   // 110592
  float* vpt      = kpt      + 110592;   // 12*768*24 = 221184
  float* qn       = vpt      + 221184;   // 9216
  float* kn       = qn       + 9216;     // 9216
  float* logits   = kn       + 9216;     // 12*768*768 = 7077888 (28.3 MB)
  float* feat     = logits   + 7077888;  // 768*2112   = 1622016
  float* rpt      = feat     + 1622016;  // 768*12*24  = 221184
  // total ~10.3M floats = 41 MB of d_ws

  // projections
  gemm_bias_kernel<<<dim3(3,12), 256, 0, stream>>>(in1d, 384, wq,   192, bq,   proj_q,   192, 768, 192, 384);
  gemm_bias_kernel<<<dim3(6,12), 256, 0, stream>>>(in1d, 384, wkv,  384, bkv,  proj_kv,  384, 768, 384, 384);
  gemm_bias_kernel<<<dim3(3,12), 256, 0, stream>>>(in1d, 384, wqp,  144, bqp,  proj_qp,  144, 768, 144, 384);
  gemm_bias_kernel<<<dim3(7,12), 256, 0, stream>>>(in1d, 384, wkvp, 432, bkvp, proj_kvp, 432, 768, 432, 384);
  // rigid transform of points
  point_transform_kernel<<<36, 256, 0, stream>>>(proj_qp, proj_kvp, rot, tra, qpt, kpt, vpt, qn, kn);
  // scalar+point logits
  logits_sp_kernel<<<dim3(12,12,12), 256, 0, stream>>>(proj_q, proj_kv, qpt, kpt, qn, kn, tpw, b2d, mask, logits);
  // += att2d (pass 1 over inputs_2d)
  att2d_kernel<<<dim3(12,768), 256, 0, stream>>>(in2d, w2d, logits);
  // softmax + res2d (pass 2 over inputs_2d); normalized attn written back
  softmax_res2d_kernel<<<768, 256, 0, stream>>>(in2d, logits, feat);
  // attn @ [vs|v_pt]
  res_sv_pt_kernel<<<dim3(12,24), 256, 0, stream>>>(logits, proj_kv, vpt, feat, rpt);
  // inverse rigid + dist
  pt_epilogue_kernel<<<288, 256, 0, stream>>>(rpt, rot, tra, feat);
  // output projection
  gemm_bias_kernel<<<dim3(6,12), 256, 0, stream>>>(feat, 2112, wout, 384, bout, out, 384, 768, 384, 2112);
}

// Round 2
// 420.383 us; speedup vs baseline: 1.7656x; 1.7656x over previous
//
#include <hip/hip_runtime.h>
#include <cstdint>
#include <cstddef>

// InvariantPointAttention N=768, H=12, C=384, PD=128, SQK=SV=16, PQK=4, PV=8.
// Round 2: flash-style fusion (single pass over inputs_2d), rank-32 logit dot,
// split-K output GEMM, merged projection GEMM.

#define N_RES 768
#define NHEAD 12
#define NN (768*768)

__device__ __forceinline__ float softplusf_(float x) {
  return (x > 20.f) ? x : log1pf(__expf(x));
}

// ---------------- pack B_all[384][1152] from 4 weight mats ------------------
__global__ __launch_bounds__(256) void pack_b_kernel(
    const float* __restrict__ wq, const float* __restrict__ wkv,
    const float* __restrict__ wqp, const float* __restrict__ wkvp,
    float* __restrict__ B_all)
{
  int idx4 = blockIdx.x * 256 + threadIdx.x;   // 110592 units
  int k = idx4 / 288;
  int n = (idx4 - k*288) * 4;
  float4 v;
  if (n < 192)       v = *(const float4*)(wq   + (size_t)k*192 + n);
  else if (n < 576)  v = *(const float4*)(wkv  + (size_t)k*384 + (n-192));
  else if (n < 720)  v = *(const float4*)(wqp  + (size_t)k*144 + (n-576));
  else               v = *(const float4*)(wkvp + (size_t)k*432 + (n-720));
  *(float4*)(B_all + (size_t)k*1152 + n) = v;
}

// ---------------- pack bias_all[1152] + wT[12][128] = s3*w2d^T --------------
__global__ __launch_bounds__(256) void pack_small_kernel(
    const float* __restrict__ bq, const float* __restrict__ bkv,
    const float* __restrict__ bqp, const float* __restrict__ bkvp,
    const float* __restrict__ w2d,
    float* __restrict__ bias_all, float* __restrict__ wT)
{
  int idx = blockIdx.x * 256 + threadIdx.x;
  if (idx < 1152) {
    float v;
    if (idx < 192)      v = bq[idx];
    else if (idx < 576) v = bkv[idx-192];
    else if (idx < 720) v = bqp[idx-576];
    else                v = bkvp[idx-720];
    bias_all[idx] = v;
  } else if (idx < 2688) {
    int t = idx - 1152;
    int h = t >> 7, c = t & 127;
    wT[h*128 + c] = 0.5773502691896258f * w2d[c*12 + h];
  }
}

// ---------------- tiled GEMM, optional split-K via gridDim.z ----------------
// C[M,N] = A[M,K(range)] @ B + bias (bias only when gridDim.z==1).
// BM=BN=64, BK=16, 256 thr, 4x4 micro. M%64==0, N%64==0, lda/ldb%4==0.
__global__ __launch_bounds__(256) void gemm_kernel(
    const float* __restrict__ A, int lda,
    const float* __restrict__ B, int ldb,
    const float* __restrict__ bias,
    float* __restrict__ C, int ldc,
    int M, int K, int kPerSplit)
{
  __shared__ float As[16][68];
  __shared__ float Bs[16][68];
  const int tid = threadIdx.x;
  const int m0 = blockIdx.y * 64, n0 = blockIdx.x * 64;
  const int kbeg = blockIdx.z * kPerSplit;
  const int kend = kbeg + kPerSplit;   // exact divisor by construction
  const int tn = tid & 15, tm = tid >> 4;
  float acc[4][4] = {};
  for (int k0 = kbeg; k0 < kend; k0 += 16) {
    {
      int idx = tid * 4;
      int m = idx >> 4, kk = idx & 15;
      float4 a = *(const float4*)(A + (size_t)(m0+m)*lda + k0 + kk);
      As[kk+0][m] = a.x; As[kk+1][m] = a.y; As[kk+2][m] = a.z; As[kk+3][m] = a.w;
    }
    {
      int kk = tid >> 4, n = (tid & 15) * 4;
      float4 b = *(const float4*)(B + (size_t)(k0+kk)*ldb + n0 + n);
      *(float4*)&Bs[kk][n] = b;
    }
    __syncthreads();
    #pragma unroll
    for (int k = 0; k < 16; ++k) {
      float4 a = *(const float4*)&As[k][tm*4];
      float4 b = *(const float4*)&Bs[k][tn*4];
      acc[0][0]=fmaf(a.x,b.x,acc[0][0]); acc[0][1]=fmaf(a.x,b.y,acc[0][1]);
      acc[0][2]=fmaf(a.x,b.z,acc[0][2]); acc[0][3]=fmaf(a.x,b.w,acc[0][3]);
      acc[1][0]=fmaf(a.y,b.x,acc[1][0]); acc[1][1]=fmaf(a.y,b.y,acc[1][1]);
      acc[1][2]=fmaf(a.y,b.z,acc[1][2]); acc[1][3]=fmaf(a.y,b.w,acc[1][3]);
      acc[2][0]=fmaf(a.z,b.x,acc[2][0]); acc[2][1]=fmaf(a.z,b.y,acc[2][1]);
      acc[2][2]=fmaf(a.z,b.z,acc[2][2]); acc[2][3]=fmaf(a.z,b.w,acc[2][3]);
      acc[3][0]=fmaf(a.w,b.x,acc[3][0]); acc[3][1]=fmaf(a.w,b.y,acc[3][1]);
      acc[3][2]=fmaf(a.w,b.z,acc[3][2]); acc[3][3]=fmaf(a.w,b.w,acc[3][3]);
    }
    __syncthreads();
  }
  float* Cp = C + (size_t)blockIdx.z * M * ldc;
  if (gridDim.z == 1) {
    #pragma unroll
    for (int r = 0; r < 4; ++r) {
      float* cp = Cp + (size_t)(m0 + tm*4 + r)*ldc + n0 + tn*4;
      #pragma unroll
      for (int c = 0; c < 4; ++c) cp[c] = acc[r][c] + bias[n0 + tn*4 + c];
    }
  } else {
    #pragma unroll
    for (int r = 0; r < 4; ++r) {
      float* cp = Cp + (size_t)(m0 + tm*4 + r)*ldc + n0 + tn*4;
      #pragma unroll
      for (int c = 0; c < 4; ++c) cp[c] = acc[r][c];
    }
  }
}

// ---------------- split-K reduce + bias for the output GEMM -----------------
__global__ __launch_bounds__(256) void reduce_out_kernel(
    const float* __restrict__ part, const float* __restrict__ bout,
    float* __restrict__ out)
{
  int idx4 = blockIdx.x * 256 + threadIdx.x;   // 73728 units
  if (idx4 >= 73728) return;
  int n4 = idx4 % 96;
  float4 a = *(const float4*)(bout + n4*4);
  #pragma unroll
  for (int z = 0; z < 6; ++z) {
    float4 p = *(const float4*)(part + (size_t)z*294912 + (size_t)idx4*4);
    a.x += p.x; a.y += p.y; a.z += p.z; a.w += p.w;
  }
  *(float4*)(out + (size_t)idx4*4) = a;
}

// ---------------- build packed U/K/V vectors (rigid transforms folded) ------
// U[i,h,32]: [sw*qs(16), pw*qpt(12), ci, 50*mi, -0.5*pw, 0]
// K[j,h,32]: [ks(16),    kpt(12),     1,  mj,    kn,     0]
// V[j,h,40]: [vs(16), vpt(24, d*8+p)]
__global__ __launch_bounds__(256) void point_pack_kernel(
    const float* __restrict__ proj, const float* __restrict__ rot,
    const float* __restrict__ tra, const float* __restrict__ tpw,
    const float* __restrict__ b2d, const float* __restrict__ mask,
    float* __restrict__ Upack, float* __restrict__ Kpack, float* __restrict__ Vpack)
{
  int idx = blockIdx.x * 256 + threadIdx.x;
  if (idx >= N_RES * NHEAD) return;
  int i = idx / NHEAD, h = idx - i*NHEAD;
  float R[9], T[3];
  #pragma unroll
  for (int r = 0; r < 9; ++r) R[r] = rot[r*N_RES + i];
  #pragma unroll
  for (int d = 0; d < 3; ++d) T[d] = tra[d*N_RES + i];
  const float pw = 0.13608276348795434f * softplusf_(tpw[h]); // sqrt(1/54)*sp
  const float sw = 0.14433756729740643f;                      // sqrt(1/48)
  const float s3 = 0.5773502691896258f;                       // sqrt(1/3)
  const float* prow = proj + (size_t)i * 1152;
  float* U  = Upack + (size_t)idx * 32;
  float* Kp = Kpack + (size_t)idx * 32;
  float* Vp = Vpack + (size_t)idx * 40;
  #pragma unroll
  for (int c = 0; c < 16; ++c) U[c]  = sw * prow[h*16 + c];
  #pragma unroll
  for (int c = 0; c < 16; ++c) Kp[c] = prow[192 + h*32 + c];
  #pragma unroll
  for (int c = 0; c < 16; ++c) Vp[c] = prow[192 + h*32 + 16 + c];
  float qn = 0.f;
  #pragma unroll
  for (int p = 0; p < 4; ++p) {
    float x = prow[576      + h*4 + p];
    float y = prow[576 + 48 + h*4 + p];
    float z = prow[576 + 96 + h*4 + p];
    #pragma unroll
    for (int d = 0; d < 3; ++d) {
      float v = R[3*d]*x + R[3*d+1]*y + R[3*d+2]*z + T[d];
      U[16 + d*4 + p] = pw * v;
      qn += v*v;
    }
  }
  float kn = 0.f;
  #pragma unroll
  for (int m = 0; m < 12; ++m) {
    float x = prow[720       + h*12 + m];
    float y = prow[720 + 144 + h*12 + m];
    float z = prow[720 + 288 + h*12 + m];
    #pragma unroll
    for (int d = 0; d < 3; ++d) {
      float v = R[3*d]*x + R[3*d+1]*y + R[3*d+2]*z + T[d];
      if (m < 4) { Kp[16 + d*4 + m] = v; kn += v*v; }
      else       { Vp[16 + d*8 + (m-4)] = v; }
    }
  }
  U[28] = -0.5f*pw*qn + s3*b2d[h] - 50.f;  U[29] = 50.f * mask[i];
  U[30] = -0.5f*pw;                        U[31] = 0.f;
  Kp[28] = 1.f;   Kp[29] = mask[i];
  Kp[30] = kn;    Kp[31] = 0.f;
}

// ---------------- fused: logits + online softmax + res2d (1 pass over in2d) -
// Block per i. wave w handles heads 3w..3w+2 (lane = j within 64-tile).
__global__ __launch_bounds__(256) void fused_attn_kernel(
    const float* __restrict__ in2d, const float* __restrict__ Upack,
    const float* __restrict__ Kpack, const float* __restrict__ wT,
    float* __restrict__ logits, float2* __restrict__ ms,
    float* __restrict__ feat)
{
  __shared__ float U[12][32];
  __shared__ float P[12][64];
  __shared__ float scale_s[12];
  __shared__ float inv_s[12];
  __shared__ float comb[12][128];
  const int i = blockIdx.x;
  const int tid = threadIdx.x;
  const int wave = tid >> 6, lane = tid & 63;
  for (int t = tid; t < 384; t += 256) U[t>>5][t&31] = Upack[(size_t)i*384 + t];
  __syncthreads();
  const int h0 = wave * 3;
  const int hu = __builtin_amdgcn_readfirstlane(h0);
  const float* w0 = wT + hu*128;
  float m_run[3] = {-1e30f, -1e30f, -1e30f};
  float s_run[3] = {0.f, 0.f, 0.f};
  const int oc = tid & 127, ohalf = tid >> 7;
  float oacc[12];
  #pragma unroll
  for (int h = 0; h < 12; ++h) oacc[h] = 0.f;

  for (int jt = 0; jt < 12; ++jt) {
    const int j0 = jt * 64;
    const int j = j0 + lane;
    float l3[3];
    // rank-32 scalar+point+mask+const dot
    #pragma unroll
    for (int r = 0; r < 3; ++r) {
      const float* kp = Kpack + ((size_t)j*12 + h0 + r) * 32;
      float a = 0.f;
      #pragma unroll
      for (int c4 = 0; c4 < 8; ++c4) {
        float4 k4 = *(const float4*)(kp + c4*4);
        float4 u4 = *(const float4*)&U[h0 + r][c4*4];
        a = fmaf(k4.x,u4.x, fmaf(k4.y,u4.y, fmaf(k4.z,u4.z, fmaf(k4.w,u4.w, a))));
      }
      l3[r] = a;
    }
    // att2d: 128-dot over this j-row, 3 heads (w uniform -> scalar loads)
    {
      const float* xrow = in2d + ((size_t)i*N_RES + j) * 128;
      float t0 = 0.f, t1 = 0.f, t2 = 0.f;
      #pragma unroll
      for (int c4 = 0; c4 < 32; ++c4) {
        float4 x  = *(const float4*)(xrow + c4*4);
        float4 wa = *(const float4*)(w0 + c4*4);
        float4 wb = *(const float4*)(w0 + 128 + c4*4);
        float4 wc = *(const float4*)(w0 + 256 + c4*4);
        t0 = fmaf(x.x,wa.x, fmaf(x.y,wa.y, fmaf(x.z,wa.z, fmaf(x.w,wa.w, t0))));
        t1 = fmaf(x.x,wb.x, fmaf(x.y,wb.y, fmaf(x.z,wb.z, fmaf(x.w,wb.w, t1))));
        t2 = fmaf(x.x,wc.x, fmaf(x.y,wc.y, fmaf(x.z,wc.z, fmaf(x.w,wc.w, t2))));
      }
      l3[0] += t0; l3[1] += t1; l3[2] += t2;
    }
    #pragma unroll
    for (int r = 0; r < 3; ++r)
      logits[(size_t)(h0+r)*NN + (size_t)i*N_RES + j] = l3[r];
    // online softmax update
    #pragma unroll
    for (int r = 0; r < 3; ++r) {
      float tmax = l3[r];
      #pragma unroll
      for (int off = 32; off; off >>= 1) tmax = fmaxf(tmax, __shfl_xor(tmax, off));
      float mnew = fmaxf(m_run[r], tmax);
      float sc = __expf(m_run[r] - mnew);
      float p = __expf(l3[r] - mnew);
      float ps = p;
      #pragma unroll
      for (int off = 32; off; off >>= 1) ps += __shfl_xor(ps, off);
      s_run[r] = s_run[r]*sc + ps;
      m_run[r] = mnew;
      P[h0 + r][lane] = p;
      if (lane == 0) scale_s[h0 + r] = sc;
    }
    __syncthreads();
    // res2d accumulate (role: channel oc, j-half ohalf); in2d tile is L1/L2-hot
    {
      const float* xb = in2d + ((size_t)i*N_RES + j0 + ohalf*32) * 128 + oc;
      #pragma unroll
      for (int h = 0; h < 12; ++h) oacc[h] *= scale_s[h];
      for (int jj = 0; jj < 32; ++jj) {
        float x = xb[(size_t)jj * 128];
        #pragma unroll
        for (int h = 0; h < 12; ++h)
          oacc[h] = fmaf(P[h][ohalf*32 + jj], x, oacc[h]);
      }
    }
    __syncthreads();
  }
  // finalize
  if (lane == 0) {
    #pragma unroll
    for (int r = 0; r < 3; ++r) {
      float inv = 1.f / s_run[r];
      inv_s[h0 + r] = inv;
      ms[(size_t)i*12 + h0 + r] = make_float2(m_run[r], inv);
    }
  }
  __syncthreads();
  if (ohalf == 1) {
    #pragma unroll
    for (int h = 0; h < 12; ++h) comb[h][oc] = oacc[h];
  }
  __syncthreads();
  if (ohalf == 0) {
    float* f = feat + (size_t)i*2112 + 576;
    #pragma unroll
    for (int h = 0; h < 12; ++h)
      f[h*128 + oc] = (oacc[h] + comb[h][oc]) * inv_s[h];
  }
}

// ---------------- attn @ [vs | v_pt] per head (exp from raw logits) ---------
__global__ __launch_bounds__(256) void res_sv_pt_kernel(
    const float* __restrict__ logits, const float2* __restrict__ ms,
    const float* __restrict__ Vpack, float* __restrict__ feat,
    float* __restrict__ rpt)
{
  __shared__ float at[32][132];
  __shared__ float vt[128][41];
  const int h = blockIdx.x;
  const int i0 = blockIdx.y * 32;
  const int tid = threadIdx.x;
  const int tn = tid & 15, tm = tid >> 4;
  float acc[2][3] = {};
  for (int j0 = 0; j0 < 768; j0 += 128) {
    for (int t = tid; t < 32*32; t += 256) {
      int ii = t >> 5, jf = t & 31;
      float2 msv = ms[(size_t)(i0+ii)*12 + h];
      float4 v = *(const float4*)(logits + (size_t)h*NN + (size_t)(i0+ii)*N_RES + j0 + jf*4);
      at[ii][jf*4+0] = __expf(v.x - msv.x) * msv.y;
      at[ii][jf*4+1] = __expf(v.y - msv.x) * msv.y;
      at[ii][jf*4+2] = __expf(v.z - msv.x) * msv.y;
      at[ii][jf*4+3] = __expf(v.w - msv.x) * msv.y;
    }
    for (int t = tid; t < 128*40; t += 256) {
      int jj = t / 40, c = t - jj*40;
      vt[jj][c] = Vpack[((size_t)(j0+jj)*12 + h)*40 + c];
    }
    __syncthreads();
    #pragma unroll 4
    for (int jj = 0; jj < 128; ++jj) {
      float a0 = at[tm*2+0][jj], a1 = at[tm*2+1][jj];
      float b0 = vt[jj][tn*3+0], b1 = vt[jj][tn*3+1], b2 = vt[jj][tn*3+2];
      acc[0][0] = fmaf(a0, b0, acc[0][0]);
      acc[0][1] = fmaf(a0, b1, acc[0][1]);
      acc[0][2] = fmaf(a0, b2, acc[0][2]);
      acc[1][0] = fmaf(a1, b0, acc[1][0]);
      acc[1][1] = fmaf(a1, b1, acc[1][1]);
      acc[1][2] = fmaf(a1, b2, acc[1][2]);
    }
    __syncthreads();
  }
  #pragma unroll
  for (int r = 0; r < 2; ++r) {
    int i = i0 + tm*2 + r;
    #pragma unroll
    for (int c = 0; c < 3; ++c) {
      int col = tn*3 + c;
      if (col < 16)      feat[(size_t)i*2112 + h*16 + col] = acc[r][c];
      else if (col < 40) rpt[((size_t)i*NHEAD + h)*24 + (col-16)] = acc[r][c];
    }
  }
}

// ---------------- point epilogue: inverse rigid + dist ----------------------
__global__ __launch_bounds__(256) void pt_epilogue_kernel(
    const float* __restrict__ rpt,
    const float* __restrict__ rot, const float* __restrict__ tra,
    float* __restrict__ feat)
{
  int idx = blockIdx.x * 256 + threadIdx.x;
  if (idx >= N_RES * 96) return;
  int i = idx / 96, m = idx - i*96;
  int h = m >> 3, p = m & 7;
  const float* rp = rpt + ((size_t)i*NHEAD + h)*24 + p;
  float gx = rp[0]  - tra[i];
  float gy = rp[8]  - tra[N_RES + i];
  float gz = rp[16] - tra[2*N_RES + i];
  float lx = rot[0*N_RES+i]*gx + rot[3*N_RES+i]*gy + rot[6*N_RES+i]*gz;
  float ly = rot[1*N_RES+i]*gx + rot[4*N_RES+i]*gy + rot[7*N_RES+i]*gz;
  float lz = rot[2*N_RES+i]*gx + rot[5*N_RES+i]*gy + rot[8*N_RES+i]*gz;
  float dist = sqrtf(1e-8f + lx*lx + ly*ly + lz*lz);
  float* f = feat + (size_t)i*2112 + 192;
  f[m]       = lx;
  f[96 + m]  = ly;
  f[192 + m] = lz;
  f[288 + m] = dist;
}

extern "C" void kernel_launch(void* const* d_in, const int* in_sizes, int n_in,
                              void* d_out, int out_size, void* d_ws, size_t ws_size,
                              hipStream_t stream)
{
  const float* in1d = (const float*)d_in[0];
  const float* in2d = (const float*)d_in[1];
  const float* mask = (const float*)d_in[2];
  const float* rot  = (const float*)d_in[3];
  const float* tra  = (const float*)d_in[4];
  const float* wq   = (const float*)d_in[5];
  const float* bq   = (const float*)d_in[6];
  const float* wkv  = (const float*)d_in[7];
  const float* bkv  = (const float*)d_in[8];
  const float* wqp  = (const float*)d_in[9];
  const float* bqp  = (const float*)d_in[10];
  const float* wkvp = (const float*)d_in[11];
  const float* bkvp = (const float*)d_in[12];
  const float* tpw  = (const float*)d_in[13];
  const float* w2d  = (const float*)d_in[14];
  const float* b2d  = (const float*)d_in[15];
  const float* wout = (const float*)d_in[16];
  const float* bout = (const float*)d_in[17];
  float* out = (float*)d_out;

  float* ws = (float*)d_ws;
  // regionA (dead before out-GEMM) is reused for split-K partials.
  float* part     = ws;                   // 6*294912 = 1769472 (aliases below)
  float* proj_all = ws;                   // 884736
  float* B_all    = ws + 884736;          // 442368
  float* bias_all = ws + 1327104;         // 1152
  float* Upack    = ws + 1328256;         // 294912
  float* Kpack    = ws + 1623168;         // 294912   (regionA end 1918080)
  float* Vpack    = ws + 1918080;         // 368640
  float* wT       = ws + 2286720;         // 1536
  float* msbuf    = ws + 2288256;         // 18432 (float2 x 9216)
  float* rpt      = ws + 2306688;         // 221184
  float* feat     = ws + 2527872;         // 1622016
  float* logits   = ws + 4149888;         // 7077888
  // total 11227776 floats = 44.9 MB

  pack_b_kernel<<<432, 256, 0, stream>>>(wq, wkv, wqp, wkvp, B_all);
  pack_small_kernel<<<11, 256, 0, stream>>>(bq, bkv, bqp, bkvp, w2d, bias_all, wT);
  // merged projections: proj_all[768][1152] = in1d @ B_all + bias_all
  gemm_kernel<<<dim3(18,12,1), 256, 0, stream>>>(in1d, 384, B_all, 1152, bias_all,
                                                 proj_all, 1152, 768, 384, 384);
  point_pack_kernel<<<36, 256, 0, stream>>>(proj_all, rot, tra, tpw, b2d, mask,
                                            Upack, Kpack, Vpack);
  fused_attn_kernel<<<768, 256, 0, stream>>>(in2d, Upack, Kpack, wT,
                                             logits, (float2*)msbuf, feat);
  res_sv_pt_kernel<<<dim3(12,24), 256, 0, stream>>>(logits, (const float2*)msbuf,
                                                    Vpack, feat, rpt);
  pt_epilogue_kernel<<<288, 256, 0, stream>>>(rpt, rot, tra, feat);
  // output GEMM, split-K z=6 into part, then reduce+bias
  gemm_kernel<<<dim3(6,12,6), 256, 0, stream>>>(feat, 2112, wout, 384, nullptr,
                                                part, 384, 768, 2112, 352);
  reduce_out_kernel<<<288, 256, 0, stream>>>(part, bout, out);
}